// Round 8
// baseline (467.398 us; speedup 1.0000x reference)
//
#include <hip/hip_runtime.h>

// WarmStartSinkhornLinear on MI355X — round 8.
// Scaling-form Sinkhorn + 256x256 bf16 MFMA GEMM (8-phase schedule).
// Round-8 changes (GEMM only):
//  (a) 32x32x16 MFMA (2382 TF ceiling vs 2075 for 16x16x32; half the MFMA
//      instruction count). Per-wave output 128x64 = 4M x 2N frags of 32x32.
//  (b) 3-ahead staging with vmcnt(8) (never 0 until tail): stage {A,B}(h+3)
//      while consuming half h; each wait is almost-always satisfied.
// Slot ring and chunk-XOR swizzle unchanged (re-verified conflict-free for
// the 32x32 fragment read pattern).

#define L2E 1.44269504088896340736f

typedef __attribute__((ext_vector_type(8))) short bf16x8;
typedef __attribute__((ext_vector_type(4))) float f32x4;
typedef __attribute__((ext_vector_type(16))) float f32x16;

__device__ __forceinline__ unsigned short f2bf(float x) {
  unsigned u = __float_as_uint(x);
  u += 0x7fffu + ((u >> 16) & 1u);  // RNE
  return (unsigned short)(u >> 16);
}
__device__ __forceinline__ float bf2f(short x) {
  return __uint_as_float(((unsigned)(unsigned short)x) << 16);
}

// ---- E[row,:] = bf16(exp(10*W[row,:] - rowmax)); one block per row.
__global__ void prep_e(const float* __restrict__ W, unsigned short* __restrict__ E) {
  const int row = blockIdx.x;
  const int t = threadIdx.x;
  const float* wp = W + ((size_t)row << 12);
  float v[16];
  float m = -3.4e38f;
#pragma unroll
  for (int ch = 0; ch < 4; ++ch) {
    float4 wv = *(const float4*)(wp + ch * 1024 + t * 4);
    float a0 = 10.f * wv.x, a1 = 10.f * wv.y, a2 = 10.f * wv.z, a3 = 10.f * wv.w;
    v[ch * 4 + 0] = a0; v[ch * 4 + 1] = a1; v[ch * 4 + 2] = a2; v[ch * 4 + 3] = a3;
    m = fmaxf(m, fmaxf(fmaxf(a0, a1), fmaxf(a2, a3)));
  }
#pragma unroll
  for (int off = 32; off > 0; off >>= 1) m = fmaxf(m, __shfl_xor(m, off));
  __shared__ float sm[4];
  if ((t & 63) == 0) sm[t >> 6] = m;
  __syncthreads();
  m = fmaxf(fmaxf(sm[0], sm[1]), fmaxf(sm[2], sm[3]));
  unsigned short* ep = E + ((size_t)row << 12);
#pragma unroll
  for (int ch = 0; ch < 4; ++ch) {
    ushort4 o;
    o.x = f2bf(exp2f((v[ch * 4 + 0] - m) * L2E));
    o.y = f2bf(exp2f((v[ch * 4 + 1] - m) * L2E));
    o.z = f2bf(exp2f((v[ch * 4 + 2] - m) * L2E));
    o.w = f2bf(exp2f((v[ch * 4 + 3] - m) * L2E));
    *(ushort4*)(ep + ch * 1024 + t * 4) = o;
  }
}

// ---- ET[j][i] = E[i][j]; 64x64 bf16 tiles via LDS.
__global__ void transpose_bf(const unsigned short* __restrict__ E,
                             unsigned short* __restrict__ ET) {
  __shared__ unsigned short tile[64][66];
  const int t = threadIdx.x;
  const int r = t >> 3;
  const int c8 = (t & 7) << 3;
  const size_t i0 = (size_t)blockIdx.y << 6;
  const size_t j0 = (size_t)blockIdx.x << 6;
#pragma unroll
  for (int h = 0; h < 2; ++h) {
    bf16x8 vv = *(const bf16x8*)(E + (i0 + h * 32 + r) * 4096 + j0 + c8);
#pragma unroll
    for (int e = 0; e < 8; ++e) tile[h * 32 + r][c8 + e] = (unsigned short)vv[e];
  }
  __syncthreads();
#pragma unroll
  for (int h = 0; h < 2; ++h) {
    bf16x8 vv;
#pragma unroll
    for (int e = 0; e < 8; ++e) vv[e] = (short)tile[c8 + e][h * 32 + r];
    *(bf16x8*)(ET + (j0 + h * 32 + r) * 4096 + i0 + c8) = vv;
  }
}

// ---- u[i] = exp(c_prev[i])
__global__ void init_u(const float* __restrict__ c_prev, float* __restrict__ u) {
  const int i = blockIdx.x * 256 + threadIdx.x;
  u[i] = exp2f(c_prev[i] * L2E);
}

// ---- out[row] = 1 / sum_j M[row][j]*uin[j]; 1 wave per row, 4 rows/block.
__global__ void recip_mv(const unsigned short* __restrict__ M,
                         const float* __restrict__ uin, float* __restrict__ vout) {
  const int t = threadIdx.x;
  const int l = t & 63, w = t >> 6;
  const int row = (blockIdx.x << 2) + w;
  const unsigned short* mp = M + ((size_t)row << 12);
  float s = 0.f;
#pragma unroll
  for (int ch = 0; ch < 8; ++ch) {
    const int j = (ch << 9) + (l << 3);
    bf16x8 e = *(const bf16x8*)(mp + j);
    const float4 u0 = *(const float4*)(uin + j);
    const float4 u1 = *(const float4*)(uin + j + 4);
    s = fmaf(bf2f(e[0]), u0.x, s);
    s = fmaf(bf2f(e[1]), u0.y, s);
    s = fmaf(bf2f(e[2]), u0.z, s);
    s = fmaf(bf2f(e[3]), u0.w, s);
    s = fmaf(bf2f(e[4]), u1.x, s);
    s = fmaf(bf2f(e[5]), u1.y, s);
    s = fmaf(bf2f(e[6]), u1.z, s);
    s = fmaf(bf2f(e[7]), u1.w, s);
  }
#pragma unroll
  for (int off = 32; off > 0; off >>= 1) s += __shfl_xor(s, off);
  if (l == 0) vout[row] = 1.f / s;
}

// ---- xb[t,j] = bf16(x[t,j] * u[j])
__global__ void scale_x(const float* __restrict__ X, const float* __restrict__ u,
                        unsigned short* __restrict__ Y) {
  const size_t idx = ((size_t)blockIdx.x * 256 + threadIdx.x) * 4;
  const int col = (int)(idx & 4095);
  float4 xv = *(const float4*)(X + idx);
  float4 uu = *(const float4*)(u + col);
  ushort4 o;
  o.x = f2bf(xv.x * uu.x);
  o.y = f2bf(xv.y * uu.y);
  o.z = f2bf(xv.z * uu.z);
  o.w = f2bf(xv.w * uu.w);
  *(ushort4*)(Y + idx) = o;
}

// ---- C[m,n] = v[n] * sum_k A[m,k]*B[n,k]; A [8192,4096], B [4096,4096] bf16.
// 256x256 tile, 8 waves (2Mx4N), per-wave 128x64 = 4Mx2N frags of 32x32.
// k-half h = 32 K-elems; slot = h&3. A slots @ [s*8192) hw, B @ [32768+s*8192).
// Slot layout [256 rows][32 k], phys 8-hw chunk = c ^ ((row>>1)&3).
// Per half h: 2 phases (M-pair 0/1): {4|8 ds_read_b128, stage one half of
// h+3, barrier, lgkmcnt(0), 8 MFMA 32x32x16, [vmcnt], barrier}.
// vmcnt(8) at end of (h,1): drains {A,B}(h+1) (3-ahead staging).
__global__ __launch_bounds__(512, 2) void gemm_bt(const unsigned short* __restrict__ A,
                                                  const unsigned short* __restrict__ B,
                                                  const float* __restrict__ vscale,
                                                  float* __restrict__ C) {
  __shared__ unsigned short lds[65536];  // 128 KB
  const int t = threadIdx.x;
  const int l = t & 63;
  const int w = t >> 6;          // 0..7
  const int wm = w >> 2, wn = w & 3;

  // XCD-bijective swizzle (512 % 8 == 0) + GROUP_M=4
  int pid = blockIdx.x;
  pid = (pid & 7) * 64 + (pid >> 3);
  const int grp = pid >> 6;
  const int rem = pid & 63;
  const int bm = (grp << 2) + (rem & 3);
  const int bn = rem >> 2;
  const int m0 = bm << 8;
  const int n0 = bn << 8;

  // staging: thread t writes LDS row (t>>2), physical chunk (t&3); fetch the
  // logical chunk that belongs there: logical = (t&3) ^ f(row), f(r)=(r>>1)&3.
  const int ca = (((t & 3) ^ ((t >> 3) & 3)) << 3);
  const unsigned short* gA = A + (size_t)(m0 + (t >> 2)) * 4096 + ca;
  const unsigned short* gB = B + (size_t)(n0 + (t >> 2)) * 4096 + ca;

  // ds_read (32x32 frags): lane l reads row base+(l&31), logical chunk
  // 2*ks + (l>>5); phys = logical ^ ((l>>1)&3). Octet bank-starts are a
  // permutation of the 8 quad-bank slots -> conflict-free.
  const int fl = (l >> 1) & 3;
  const int ck0 = (((l >> 5) ^ fl) << 3);
  const int ck1 = (((2 | (l >> 5)) ^ fl) << 3);
  const int aBase = (wm * 128 + (l & 31)) * 32;  // + mi*1024 + ck[ks]
  const int bBase = (wn * 64 + (l & 31)) * 32;   // + nj*1024 + ck[ks]

  auto stage = [&](const unsigned short* gbase, int h, int isB) {
    const int slot = h & 3;
    const unsigned short* g = gbase + (size_t)h * 32;
#pragma unroll
    for (int ra = 0; ra < 2; ++ra)
      __builtin_amdgcn_global_load_lds(
          (const __attribute__((address_space(1))) void*)(g + (size_t)ra * 524288),
          (__attribute__((address_space(3))) void*)((char*)lds + isB * 65536 + slot * 16384 + ra * 8192 + w * 1024),
          16, 0, 0);
  };

  f32x16 acc[4][2] = {};
  bf16x8 afr[4], bfr[4];

  // Prologue: stage halves 0,1,2 (12 loads); vmcnt(8) -> half 0 landed.
  stage(gA, 0, 0); stage(gB, 0, 1);
  stage(gA, 1, 0); stage(gB, 1, 1);
  stage(gA, 2, 0); stage(gB, 2, 1);
  asm volatile("s_waitcnt vmcnt(8)" ::: "memory");
  __builtin_amdgcn_s_barrier();

#define MFMA32(a, b, c) __builtin_amdgcn_mfma_f32_32x32x16_bf16(a, b, c, 0, 0, 0)

#define PH0(HV, SLOT)                                                          \
  {                                                                            \
    const unsigned short* aL = lds + (SLOT) * 8192 + aBase;                    \
    const unsigned short* bL = lds + 32768 + (SLOT) * 8192 + bBase;            \
    afr[0] = *(const bf16x8*)(aL + ck0);                                       \
    afr[1] = *(const bf16x8*)(aL + ck1);                                       \
    afr[2] = *(const bf16x8*)(aL + 1024 + ck0);                                \
    afr[3] = *(const bf16x8*)(aL + 1024 + ck1);                                \
    bfr[0] = *(const bf16x8*)(bL + ck0);                                       \
    bfr[1] = *(const bf16x8*)(bL + ck1);                                       \
    bfr[2] = *(const bf16x8*)(bL + 1024 + ck0);                                \
    bfr[3] = *(const bf16x8*)(bL + 1024 + ck1);                                \
    if ((HV) <= 124) stage(gA, (HV) + 3, 0);                                   \
    __builtin_amdgcn_s_barrier();                                              \
    asm volatile("s_waitcnt lgkmcnt(0)" ::: "memory");                         \
    __builtin_amdgcn_sched_barrier(0);                                         \
    __builtin_amdgcn_s_setprio(1);                                             \
    acc[0][0] = MFMA32(afr[0], bfr[0], acc[0][0]);                             \
    acc[0][1] = MFMA32(afr[0], bfr[2], acc[0][1]);                             \
    acc[1][0] = MFMA32(afr[2], bfr[0], acc[1][0]);                             \
    acc[1][1] = MFMA32(afr[2], bfr[2], acc[1][1]);                             \
    acc[0][0] = MFMA32(afr[1], bfr[1], acc[0][0]);                             \
    acc[0][1] = MFMA32(afr[1], bfr[3], acc[0][1]);                             \
    acc[1][0] = MFMA32(afr[3], bfr[1], acc[1][0]);                             \
    acc[1][1] = MFMA32(afr[3], bfr[3], acc[1][1]);                             \
    __builtin_amdgcn_s_setprio(0);                                             \
    __builtin_amdgcn_s_barrier();                                              \
  }

#define PH1(HV, SLOT)                                                          \
  {                                                                            \
    const unsigned short* aL = lds + (SLOT) * 8192 + aBase;                    \
    afr[0] = *(const bf16x8*)(aL + 2048 + ck0);                                \
    afr[1] = *(const bf16x8*)(aL + 2048 + ck1);                                \
    afr[2] = *(const bf16x8*)(aL + 3072 + ck0);                                \
    afr[3] = *(const bf16x8*)(aL + 3072 + ck1);                                \
    if ((HV) <= 124) stage(gB, (HV) + 3, 1);                                   \
    __builtin_amdgcn_s_barrier();                                              \
    asm volatile("s_waitcnt lgkmcnt(0)" ::: "memory");                         \
    __builtin_amdgcn_sched_barrier(0);                                         \
    __builtin_amdgcn_s_setprio(1);                                             \
    acc[2][0] = MFMA32(afr[0], bfr[0], acc[2][0]);                             \
    acc[2][1] = MFMA32(afr[0], bfr[2], acc[2][1]);                             \
    acc[3][0] = MFMA32(afr[2], bfr[0], acc[3][0]);                             \
    acc[3][1] = MFMA32(afr[2], bfr[2], acc[3][1]);                             \
    acc[2][0] = MFMA32(afr[1], bfr[1], acc[2][0]);                             \
    acc[2][1] = MFMA32(afr[1], bfr[3], acc[2][1]);                             \
    acc[3][0] = MFMA32(afr[3], bfr[1], acc[3][0]);                             \
    acc[3][1] = MFMA32(afr[3], bfr[3], acc[3][1]);                             \
    __builtin_amdgcn_s_setprio(0);                                             \
    if ((HV) <= 124)      asm volatile("s_waitcnt vmcnt(8)" ::: "memory");     \
    else if ((HV) == 125) asm volatile("s_waitcnt vmcnt(4)" ::: "memory");     \
    else if ((HV) == 126) asm volatile("s_waitcnt vmcnt(0)" ::: "memory");     \
    __builtin_amdgcn_s_barrier();                                              \
  }

  for (int h = 0; h < 128; h += 4) {
    PH0(h + 0, 0) PH1(h + 0, 0)
    PH0(h + 1, 1) PH1(h + 1, 1)
    PH0(h + 2, 2) PH1(h + 2, 2)
    PH0(h + 3, 3) PH1(h + 3, 3)
  }
#undef PH0
#undef PH1
#undef MFMA32

  // Epilogue: C[m,n] = acc * v[n]. 32x32 C/D: col = l&31,
  // row = (reg&3) + 8*(reg>>2) + 4*(l>>5).
  const int ccol = l & 31;
  const int rbase = 4 * (l >> 5);
#pragma unroll
  for (int nj = 0; nj < 2; ++nj) {
    const int colj = n0 + wn * 64 + nj * 32 + ccol;
    const float vs = vscale[colj];
#pragma unroll
    for (int mi = 0; mi < 4; ++mi) {
      const int row0 = m0 + wm * 128 + mi * 32 + rbase;
#pragma unroll
      for (int r = 0; r < 16; ++r) {
        const int rowi = row0 + (r & 3) + 8 * (r >> 2);
        C[((size_t)rowi << 12) + colj] = acc[mi][nj][r] * vs;
      }
    }
  }
}

extern "C" void kernel_launch(void* const* d_in, const int* in_sizes, int n_in,
                              void* d_out, int out_size, void* d_ws, size_t ws_size,
                              hipStream_t stream) {
  const float* x      = (const float*)d_in[0];   // [4,2048,4096] f32
  const float* weight = (const float*)d_in[1];   // [4096,4096] f32
  const float* c_prev = (const float*)d_in[3];   // [1,4096] f32; r_prev unused
  float* out = (float*)d_out;

  char* ws = (char*)d_ws;
  float* u = (float*)ws;                                   // 4096 f32
  float* v = (float*)(ws + (16 << 10));                    // 4096 f32
  unsigned short* E  = (unsigned short*)(ws + (64 << 10)); // 33.5 MB
  unsigned short* ET = E + (size_t)4096 * 4096;            // 33.5 MB (dead after iters)
  unsigned short* xb = ET;                                 // xb overlays ET (67 MB)

  prep_e<<<4096, 256, 0, stream>>>(weight, E);
  transpose_bf<<<dim3(64, 64), 256, 0, stream>>>(E, ET);
  init_u<<<16, 256, 0, stream>>>(c_prev, u);

  for (int it = 0; it < 10; ++it) {
    recip_mv<<<1024, 256, 0, stream>>>(E, u, v);   // v = 1/(E u)
    recip_mv<<<1024, 256, 0, stream>>>(ET, v, u);  // u = 1/(E^T v)
  }

  scale_x<<<32768, 256, 0, stream>>>(x, u, xb);    // xb = bf16(x * u), kills ET

  gemm_bt<<<512, 512, 0, stream>>>(xb, E, v, out);
}

// Round 9
// 466.321 us; speedup vs baseline: 1.0023x; 1.0023x over previous
//
#include <hip/hip_runtime.h>

// WarmStartSinkhornLinear on MI355X — round 9.
// Scaling-form Sinkhorn + 256x256 bf16 MFMA GEMM, 32x32x16 MFMA, 8-phase
// schedule, 3-ahead staging with counted vmcnt(8).
// Round-9 change: k-chunk STORAGE order permuted by the bit-swap involution
// g = {0->0, 1->2, 2->1, 3->3} before the row-XOR. Bank model (validated on
// rounds 3/7/8 PMC): LDS groups lane i with lane i+32; an MFMA-operand read
// has lanes i/i+32 at the SAME row with logical chunks differing by 1, so
// storage must separate those chunks by 2 (banks by 8). phys = g(c) ^ f(row),
// f(r) = (r>>1)&3. Enumerated conflict-free for octets AND {i,i+32} pairs.

#define L2E 1.44269504088896340736f

typedef __attribute__((ext_vector_type(8))) short bf16x8;
typedef __attribute__((ext_vector_type(4))) float f32x4;
typedef __attribute__((ext_vector_type(16))) float f32x16;

__device__ __forceinline__ unsigned short f2bf(float x) {
  unsigned u = __float_as_uint(x);
  u += 0x7fffu + ((u >> 16) & 1u);  // RNE
  return (unsigned short)(u >> 16);
}
__device__ __forceinline__ float bf2f(short x) {
  return __uint_as_float(((unsigned)(unsigned short)x) << 16);
}

// ---- E[row,:] = bf16(exp(10*W[row,:] - rowmax)); one block per row.
__global__ void prep_e(const float* __restrict__ W, unsigned short* __restrict__ E) {
  const int row = blockIdx.x;
  const int t = threadIdx.x;
  const float* wp = W + ((size_t)row << 12);
  float v[16];
  float m = -3.4e38f;
#pragma unroll
  for (int ch = 0; ch < 4; ++ch) {
    float4 wv = *(const float4*)(wp + ch * 1024 + t * 4);
    float a0 = 10.f * wv.x, a1 = 10.f * wv.y, a2 = 10.f * wv.z, a3 = 10.f * wv.w;
    v[ch * 4 + 0] = a0; v[ch * 4 + 1] = a1; v[ch * 4 + 2] = a2; v[ch * 4 + 3] = a3;
    m = fmaxf(m, fmaxf(fmaxf(a0, a1), fmaxf(a2, a3)));
  }
#pragma unroll
  for (int off = 32; off > 0; off >>= 1) m = fmaxf(m, __shfl_xor(m, off));
  __shared__ float sm[4];
  if ((t & 63) == 0) sm[t >> 6] = m;
  __syncthreads();
  m = fmaxf(fmaxf(sm[0], sm[1]), fmaxf(sm[2], sm[3]));
  unsigned short* ep = E + ((size_t)row << 12);
#pragma unroll
  for (int ch = 0; ch < 4; ++ch) {
    ushort4 o;
    o.x = f2bf(exp2f((v[ch * 4 + 0] - m) * L2E));
    o.y = f2bf(exp2f((v[ch * 4 + 1] - m) * L2E));
    o.z = f2bf(exp2f((v[ch * 4 + 2] - m) * L2E));
    o.w = f2bf(exp2f((v[ch * 4 + 3] - m) * L2E));
    *(ushort4*)(ep + ch * 1024 + t * 4) = o;
  }
}

// ---- ET[j][i] = E[i][j]; 64x64 bf16 tiles via LDS.
__global__ void transpose_bf(const unsigned short* __restrict__ E,
                             unsigned short* __restrict__ ET) {
  __shared__ unsigned short tile[64][66];
  const int t = threadIdx.x;
  const int r = t >> 3;
  const int c8 = (t & 7) << 3;
  const size_t i0 = (size_t)blockIdx.y << 6;
  const size_t j0 = (size_t)blockIdx.x << 6;
#pragma unroll
  for (int h = 0; h < 2; ++h) {
    bf16x8 vv = *(const bf16x8*)(E + (i0 + h * 32 + r) * 4096 + j0 + c8);
#pragma unroll
    for (int e = 0; e < 8; ++e) tile[h * 32 + r][c8 + e] = (unsigned short)vv[e];
  }
  __syncthreads();
#pragma unroll
  for (int h = 0; h < 2; ++h) {
    bf16x8 vv;
#pragma unroll
    for (int e = 0; e < 8; ++e) vv[e] = (short)tile[c8 + e][h * 32 + r];
    *(bf16x8*)(ET + (j0 + h * 32 + r) * 4096 + i0 + c8) = vv;
  }
}

// ---- u[i] = exp(c_prev[i])
__global__ void init_u(const float* __restrict__ c_prev, float* __restrict__ u) {
  const int i = blockIdx.x * 256 + threadIdx.x;
  u[i] = exp2f(c_prev[i] * L2E);
}

// ---- out[row] = 1 / sum_j M[row][j]*uin[j]; 1 wave per row, 4 rows/block.
__global__ void recip_mv(const unsigned short* __restrict__ M,
                         const float* __restrict__ uin, float* __restrict__ vout) {
  const int t = threadIdx.x;
  const int l = t & 63, w = t >> 6;
  const int row = (blockIdx.x << 2) + w;
  const unsigned short* mp = M + ((size_t)row << 12);
  float s = 0.f;
#pragma unroll
  for (int ch = 0; ch < 8; ++ch) {
    const int j = (ch << 9) + (l << 3);
    bf16x8 e = *(const bf16x8*)(mp + j);
    const float4 u0 = *(const float4*)(uin + j);
    const float4 u1 = *(const float4*)(uin + j + 4);
    s = fmaf(bf2f(e[0]), u0.x, s);
    s = fmaf(bf2f(e[1]), u0.y, s);
    s = fmaf(bf2f(e[2]), u0.z, s);
    s = fmaf(bf2f(e[3]), u0.w, s);
    s = fmaf(bf2f(e[4]), u1.x, s);
    s = fmaf(bf2f(e[5]), u1.y, s);
    s = fmaf(bf2f(e[6]), u1.z, s);
    s = fmaf(bf2f(e[7]), u1.w, s);
  }
#pragma unroll
  for (int off = 32; off > 0; off >>= 1) s += __shfl_xor(s, off);
  if (l == 0) vout[row] = 1.f / s;
}

// ---- xb[t,j] = bf16(x[t,j] * u[j])
__global__ void scale_x(const float* __restrict__ X, const float* __restrict__ u,
                        unsigned short* __restrict__ Y) {
  const size_t idx = ((size_t)blockIdx.x * 256 + threadIdx.x) * 4;
  const int col = (int)(idx & 4095);
  float4 xv = *(const float4*)(X + idx);
  float4 uu = *(const float4*)(u + col);
  ushort4 o;
  o.x = f2bf(xv.x * uu.x);
  o.y = f2bf(xv.y * uu.y);
  o.z = f2bf(xv.z * uu.z);
  o.w = f2bf(xv.w * uu.w);
  *(ushort4*)(Y + idx) = o;
}

// ---- C[m,n] = v[n] * sum_k A[m,k]*B[n,k]; A [8192,4096], B [4096,4096] bf16.
// 256x256 tile, 8 waves (2Mx4N), per-wave 128x64 = 4Mx2N frags of 32x32.
// k-half h = 32 K-elems; slot = h&3. A slots @ [s*8192) hw, B @ [32768+s*8192).
// Slot layout [256 rows][32 k]; storage position of logical chunk c at row r:
//   p = g(c) ^ f(r),  g = bit-swap involution {0,2,1,3},  f(r) = (r>>1)&3.
// Per half h: 2 phases: {4|8 ds_read_b128, stage one half of h+3, barrier,
// lgkmcnt(0), 8 MFMA 32x32x16, [vmcnt], barrier}. vmcnt(8) at end of (h,1).
__global__ __launch_bounds__(512, 2) void gemm_bt(const unsigned short* __restrict__ A,
                                                  const unsigned short* __restrict__ B,
                                                  const float* __restrict__ vscale,
                                                  float* __restrict__ C) {
  __shared__ unsigned short lds[65536];  // 128 KB
  const int t = threadIdx.x;
  const int l = t & 63;
  const int w = t >> 6;          // 0..7
  const int wm = w >> 2, wn = w & 3;

  // XCD-bijective swizzle (512 % 8 == 0) + GROUP_M=4
  int pid = blockIdx.x;
  pid = (pid & 7) * 64 + (pid >> 3);
  const int grp = pid >> 6;
  const int rem = pid & 63;
  const int bm = (grp << 2) + (rem & 3);
  const int bn = rem >> 2;
  const int m0 = bm << 8;
  const int n0 = bn << 8;

  // staging: thread t writes LDS row (t>>2), storage position p = t&3; the
  // logical chunk living there is c = g(p ^ f(row)), f(row) = (t>>3)&3.
  const int pc = (t & 3) ^ ((t >> 3) & 3);
  const int gc = ((pc & 1) << 1) | ((pc >> 1) & 1);  // g(pc)
  const int ca = gc << 3;
  const unsigned short* gA = A + (size_t)(m0 + (t >> 2)) * 4096 + ca;
  const unsigned short* gB = B + (size_t)(n0 + (t >> 2)) * 4096 + ca;

  // ds_read (32x32 frags): lane l reads row base+(l&31); ks=0 wants logical
  // chunk (l>>5) -> position g(l>>5)^f = ((l>>5)<<1)^f; ks=1 wants logical
  // 2|(l>>5) -> position (1|((l>>5)<<1))^f. f = (l>>1)&3 (row = l&31).
  // Conflict-free under both octet and {i,i+32} groupings (enumerated).
  const int fl = (l >> 1) & 3;
  const int ck0 = ((((l >> 5) << 1) ^ fl) << 3);
  const int ck1 = (((1 | ((l >> 5) << 1)) ^ fl) << 3);
  const int aBase = (wm * 128 + (l & 31)) * 32;  // + mi*1024 + ck[ks]
  const int bBase = (wn * 64 + (l & 31)) * 32;   // + nj*1024 + ck[ks]

  auto stage = [&](const unsigned short* gbase, int h, int isB) {
    const int slot = h & 3;
    const unsigned short* g = gbase + (size_t)h * 32;
#pragma unroll
    for (int ra = 0; ra < 2; ++ra)
      __builtin_amdgcn_global_load_lds(
          (const __attribute__((address_space(1))) void*)(g + (size_t)ra * 524288),
          (__attribute__((address_space(3))) void*)((char*)lds + isB * 65536 + slot * 16384 + ra * 8192 + w * 1024),
          16, 0, 0);
  };

  f32x16 acc[4][2] = {};
  bf16x8 afr[4], bfr[4];

  // Prologue: stage halves 0,1,2 (12 loads); vmcnt(8) -> half 0 landed.
  stage(gA, 0, 0); stage(gB, 0, 1);
  stage(gA, 1, 0); stage(gB, 1, 1);
  stage(gA, 2, 0); stage(gB, 2, 1);
  asm volatile("s_waitcnt vmcnt(8)" ::: "memory");
  __builtin_amdgcn_s_barrier();

#define MFMA32(a, b, c) __builtin_amdgcn_mfma_f32_32x32x16_bf16(a, b, c, 0, 0, 0)

#define PH0(HV, SLOT)                                                          \
  {                                                                            \
    const unsigned short* aL = lds + (SLOT) * 8192 + aBase;                    \
    const unsigned short* bL = lds + 32768 + (SLOT) * 8192 + bBase;            \
    afr[0] = *(const bf16x8*)(aL + ck0);                                       \
    afr[1] = *(const bf16x8*)(aL + ck1);                                       \
    afr[2] = *(const bf16x8*)(aL + 1024 + ck0);                                \
    afr[3] = *(const bf16x8*)(aL + 1024 + ck1);                                \
    bfr[0] = *(const bf16x8*)(bL + ck0);                                       \
    bfr[1] = *(const bf16x8*)(bL + ck1);                                       \
    bfr[2] = *(const bf16x8*)(bL + 1024 + ck0);                                \
    bfr[3] = *(const bf16x8*)(bL + 1024 + ck1);                                \
    if ((HV) <= 124) stage(gA, (HV) + 3, 0);                                   \
    __builtin_amdgcn_s_barrier();                                              \
    asm volatile("s_waitcnt lgkmcnt(0)" ::: "memory");                         \
    __builtin_amdgcn_sched_barrier(0);                                         \
    __builtin_amdgcn_s_setprio(1);                                             \
    acc[0][0] = MFMA32(afr[0], bfr[0], acc[0][0]);                             \
    acc[0][1] = MFMA32(afr[0], bfr[2], acc[0][1]);                             \
    acc[1][0] = MFMA32(afr[2], bfr[0], acc[1][0]);                             \
    acc[1][1] = MFMA32(afr[2], bfr[2], acc[1][1]);                             \
    acc[0][0] = MFMA32(afr[1], bfr[1], acc[0][0]);                             \
    acc[0][1] = MFMA32(afr[1], bfr[3], acc[0][1]);                             \
    acc[1][0] = MFMA32(afr[3], bfr[1], acc[1][0]);                             \
    acc[1][1] = MFMA32(afr[3], bfr[3], acc[1][1]);                             \
    __builtin_amdgcn_s_setprio(0);                                             \
    __builtin_amdgcn_s_barrier();                                              \
  }

#define PH1(HV, SLOT)                                                          \
  {                                                                            \
    const unsigned short* aL = lds + (SLOT) * 8192 + aBase;                    \
    afr[0] = *(const bf16x8*)(aL + 2048 + ck0);                                \
    afr[1] = *(const bf16x8*)(aL + 2048 + ck1);                                \
    afr[2] = *(const bf16x8*)(aL + 3072 + ck0);                                \
    afr[3] = *(const bf16x8*)(aL + 3072 + ck1);                                \
    if ((HV) <= 124) stage(gB, (HV) + 3, 1);                                   \
    __builtin_amdgcn_s_barrier();                                              \
    asm volatile("s_waitcnt lgkmcnt(0)" ::: "memory");                         \
    __builtin_amdgcn_sched_barrier(0);                                         \
    __builtin_amdgcn_s_setprio(1);                                             \
    acc[2][0] = MFMA32(afr[0], bfr[0], acc[2][0]);                             \
    acc[2][1] = MFMA32(afr[0], bfr[2], acc[2][1]);                             \
    acc[3][0] = MFMA32(afr[2], bfr[0], acc[3][0]);                             \
    acc[3][1] = MFMA32(afr[2], bfr[2], acc[3][1]);                             \
    acc[2][0] = MFMA32(afr[1], bfr[1], acc[2][0]);                             \
    acc[2][1] = MFMA32(afr[1], bfr[3], acc[2][1]);                             \
    acc[3][0] = MFMA32(afr[3], bfr[1], acc[3][0]);                             \
    acc[3][1] = MFMA32(afr[3], bfr[3], acc[3][1]);                             \
    __builtin_amdgcn_s_setprio(0);                                             \
    if ((HV) <= 124)      asm volatile("s_waitcnt vmcnt(8)" ::: "memory");     \
    else if ((HV) == 125) asm volatile("s_waitcnt vmcnt(4)" ::: "memory");     \
    else if ((HV) == 126) asm volatile("s_waitcnt vmcnt(0)" ::: "memory");     \
    __builtin_amdgcn_s_barrier();                                              \
  }

  for (int h = 0; h < 128; h += 4) {
    PH0(h + 0, 0) PH1(h + 0, 0)
    PH0(h + 1, 1) PH1(h + 1, 1)
    PH0(h + 2, 2) PH1(h + 2, 2)
    PH0(h + 3, 3) PH1(h + 3, 3)
  }
#undef PH0
#undef PH1
#undef MFMA32

  // Epilogue: C[m,n] = acc * v[n]. 32x32 C/D: col = l&31,
  // row = (reg&3) + 8*(reg>>2) + 4*(l>>5).
  const int ccol = l & 31;
  const int rbase = 4 * (l >> 5);
#pragma unroll
  for (int nj = 0; nj < 2; ++nj) {
    const int colj = n0 + wn * 64 + nj * 32 + ccol;
    const float vs = vscale[colj];
#pragma unroll
    for (int mi = 0; mi < 4; ++mi) {
      const int row0 = m0 + wm * 128 + mi * 32 + rbase;
#pragma unroll
      for (int r = 0; r < 16; ++r) {
        const int rowi = row0 + (r & 3) + 8 * (r >> 2);
        C[((size_t)rowi << 12) + colj] = acc[mi][nj][r] * vs;
      }
    }
  }
}

extern "C" void kernel_launch(void* const* d_in, const int* in_sizes, int n_in,
                              void* d_out, int out_size, void* d_ws, size_t ws_size,
                              hipStream_t stream) {
  const float* x      = (const float*)d_in[0];   // [4,2048,4096] f32
  const float* weight = (const float*)d_in[1];   // [4096,4096] f32
  const float* c_prev = (const float*)d_in[3];   // [1,4096] f32; r_prev unused
  float* out = (float*)d_out;

  char* ws = (char*)d_ws;
  float* u = (float*)ws;                                   // 4096 f32
  float* v = (float*)(ws + (16 << 10));                    // 4096 f32
  unsigned short* E  = (unsigned short*)(ws + (64 << 10)); // 33.5 MB
  unsigned short* ET = E + (size_t)4096 * 4096;            // 33.5 MB (dead after iters)
  unsigned short* xb = ET;                                 // xb overlays ET (67 MB)

  prep_e<<<4096, 256, 0, stream>>>(weight, E);
  transpose_bf<<<dim3(64, 64), 256, 0, stream>>>(E, ET);
  init_u<<<16, 256, 0, stream>>>(c_prev, u);

  for (int it = 0; it < 10; ++it) {
    recip_mv<<<1024, 256, 0, stream>>>(E, u, v);   // v = 1/(E u)
    recip_mv<<<1024, 256, 0, stream>>>(ET, v, u);  // u = 1/(E^T v)
  }

  scale_x<<<32768, 256, 0, stream>>>(x, u, xb);    // xb = bf16(x * u), kills ET

  gemm_bt<<<512, 512, 0, stream>>>(xb, E, v, out);
}

// Round 10
// 462.929 us; speedup vs baseline: 1.0097x; 1.0073x over previous
//
#include <hip/hip_runtime.h>

// WarmStartSinkhornLinear on MI355X — round 10.
// Scaling-form Sinkhorn + 256x256 bf16 GEMM, 32x32x16 MFMA, 8-phase schedule,
// 3-ahead staging, counted vmcnt(8).
// Round-10 change: LDS slot re-paged so every MFMA-operand ds_read_b128
// reproduces the EMPIRICALLY-ZERO-CONFLICT round-7 lane->byte pattern
// (certified 0 SQ_LDS_BANK_CONFLICT on HW in rounds 4-7):
//   slot = 8 blocks (32 rows) x 2 pages (1KB); cell(r,cb) =
//   (r&15)*4 + ((bit4(r) | cb<<1) ^ ((r>>1)&3)); read offset =
//   blk*1024 + ks*512 + (l&15)*32 + (((l>>4)&3 ^ (l>>1)&3))<<3.
// Staging inverts the cell map into per-lane GLOBAL source addresses
// (global_load_lds dest stays linear per 1KB page).

#define L2E 1.44269504088896340736f

typedef __attribute__((ext_vector_type(8))) short bf16x8;
typedef __attribute__((ext_vector_type(4))) float f32x4;
typedef __attribute__((ext_vector_type(16))) float f32x16;

__device__ __forceinline__ unsigned short f2bf(float x) {
  unsigned u = __float_as_uint(x);
  u += 0x7fffu + ((u >> 16) & 1u);  // RNE
  return (unsigned short)(u >> 16);
}
__device__ __forceinline__ float bf2f(short x) {
  return __uint_as_float(((unsigned)(unsigned short)x) << 16);
}

// ---- E[row,:] = bf16(exp(10*W[row,:] - rowmax)); one block per row.
__global__ void prep_e(const float* __restrict__ W, unsigned short* __restrict__ E) {
  const int row = blockIdx.x;
  const int t = threadIdx.x;
  const float* wp = W + ((size_t)row << 12);
  float v[16];
  float m = -3.4e38f;
#pragma unroll
  for (int ch = 0; ch < 4; ++ch) {
    float4 wv = *(const float4*)(wp + ch * 1024 + t * 4);
    float a0 = 10.f * wv.x, a1 = 10.f * wv.y, a2 = 10.f * wv.z, a3 = 10.f * wv.w;
    v[ch * 4 + 0] = a0; v[ch * 4 + 1] = a1; v[ch * 4 + 2] = a2; v[ch * 4 + 3] = a3;
    m = fmaxf(m, fmaxf(fmaxf(a0, a1), fmaxf(a2, a3)));
  }
#pragma unroll
  for (int off = 32; off > 0; off >>= 1) m = fmaxf(m, __shfl_xor(m, off));
  __shared__ float sm[4];
  if ((t & 63) == 0) sm[t >> 6] = m;
  __syncthreads();
  m = fmaxf(fmaxf(sm[0], sm[1]), fmaxf(sm[2], sm[3]));
  unsigned short* ep = E + ((size_t)row << 12);
#pragma unroll
  for (int ch = 0; ch < 4; ++ch) {
    ushort4 o;
    o.x = f2bf(exp2f((v[ch * 4 + 0] - m) * L2E));
    o.y = f2bf(exp2f((v[ch * 4 + 1] - m) * L2E));
    o.z = f2bf(exp2f((v[ch * 4 + 2] - m) * L2E));
    o.w = f2bf(exp2f((v[ch * 4 + 3] - m) * L2E));
    *(ushort4*)(ep + ch * 1024 + t * 4) = o;
  }
}

// ---- ET[j][i] = E[i][j]; 64x64 bf16 tiles via LDS.
__global__ void transpose_bf(const unsigned short* __restrict__ E,
                             unsigned short* __restrict__ ET) {
  __shared__ unsigned short tile[64][66];
  const int t = threadIdx.x;
  const int r = t >> 3;
  const int c8 = (t & 7) << 3;
  const size_t i0 = (size_t)blockIdx.y << 6;
  const size_t j0 = (size_t)blockIdx.x << 6;
#pragma unroll
  for (int h = 0; h < 2; ++h) {
    bf16x8 vv = *(const bf16x8*)(E + (i0 + h * 32 + r) * 4096 + j0 + c8);
#pragma unroll
    for (int e = 0; e < 8; ++e) tile[h * 32 + r][c8 + e] = (unsigned short)vv[e];
  }
  __syncthreads();
#pragma unroll
  for (int h = 0; h < 2; ++h) {
    bf16x8 vv;
#pragma unroll
    for (int e = 0; e < 8; ++e) vv[e] = (short)tile[c8 + e][h * 32 + r];
    *(bf16x8*)(ET + (j0 + h * 32 + r) * 4096 + i0 + c8) = vv;
  }
}

// ---- u[i] = exp(c_prev[i])
__global__ void init_u(const float* __restrict__ c_prev, float* __restrict__ u) {
  const int i = blockIdx.x * 256 + threadIdx.x;
  u[i] = exp2f(c_prev[i] * L2E);
}

// ---- out[row] = 1 / sum_j M[row][j]*uin[j]; 1 wave per row, 4 rows/block.
__global__ void recip_mv(const unsigned short* __restrict__ M,
                         const float* __restrict__ uin, float* __restrict__ vout) {
  const int t = threadIdx.x;
  const int l = t & 63, w = t >> 6;
  const int row = (blockIdx.x << 2) + w;
  const unsigned short* mp = M + ((size_t)row << 12);
  float s = 0.f;
#pragma unroll
  for (int ch = 0; ch < 8; ++ch) {
    const int j = (ch << 9) + (l << 3);
    bf16x8 e = *(const bf16x8*)(mp + j);
    const float4 u0 = *(const float4*)(uin + j);
    const float4 u1 = *(const float4*)(uin + j + 4);
    s = fmaf(bf2f(e[0]), u0.x, s);
    s = fmaf(bf2f(e[1]), u0.y, s);
    s = fmaf(bf2f(e[2]), u0.z, s);
    s = fmaf(bf2f(e[3]), u0.w, s);
    s = fmaf(bf2f(e[4]), u1.x, s);
    s = fmaf(bf2f(e[5]), u1.y, s);
    s = fmaf(bf2f(e[6]), u1.z, s);
    s = fmaf(bf2f(e[7]), u1.w, s);
  }
#pragma unroll
  for (int off = 32; off > 0; off >>= 1) s += __shfl_xor(s, off);
  if (l == 0) vout[row] = 1.f / s;
}

// ---- xb[t,j] = bf16(x[t,j] * u[j])
__global__ void scale_x(const float* __restrict__ X, const float* __restrict__ u,
                        unsigned short* __restrict__ Y) {
  const size_t idx = ((size_t)blockIdx.x * 256 + threadIdx.x) * 4;
  const int col = (int)(idx & 4095);
  float4 xv = *(const float4*)(X + idx);
  float4 uu = *(const float4*)(u + col);
  ushort4 o;
  o.x = f2bf(xv.x * uu.x);
  o.y = f2bf(xv.y * uu.y);
  o.z = f2bf(xv.z * uu.z);
  o.w = f2bf(xv.w * uu.w);
  *(ushort4*)(Y + idx) = o;
}

// ---- C[m,n] = v[n] * sum_k A[m,k]*B[n,k]; A [8192,4096], B [4096,4096] bf16.
// 256x256 tile, 8 waves (2Mx4N), per-wave 128x64 = 4Mx2N frags of 32x32.
// k-half h = 32 K-elems; slot = h&3 (16KB each; A @ slot*16KB, B @ 64KB+).
// Slot = 8 blocks (32 rows, 2KB) x 2 pages (ks, 1KB); cell(r,cb) =
//   (r&15)*4 + ((((r>>4)&1) | (cb<<1)) ^ ((r>>1)&3)), cell = 16B.
// Read (blk, ks): hw = blk*1024 + ks*512 + (l&15)*32 + ((((l>>4)&3)^((l>>1)&3))<<3)
//   -> per-instruction lane->byte map == round-7's HW-certified 0-conflict map.
// Stage: wave w writes block w, pages ks=0,1 (linear 1KB dest); per-lane global
//   source from the inverted cell map.
__global__ __launch_bounds__(512, 2) void gemm_bt(const unsigned short* __restrict__ A,
                                                  const unsigned short* __restrict__ B,
                                                  const float* __restrict__ vscale,
                                                  float* __restrict__ C) {
  __shared__ unsigned short lds[65536];  // 128 KB
  const int t = threadIdx.x;
  const int l = t & 63;
  const int w = t >> 6;          // 0..7
  const int wm = w >> 2, wn = w & 3;

  // XCD-bijective swizzle (512 % 8 == 0) + GROUP_M=4
  int pid = blockIdx.x;
  pid = (pid & 7) * 64 + (pid >> 3);
  const int grp = pid >> 6;
  const int rem = pid & 63;
  const int bm = (grp << 2) + (rem & 3);
  const int bn = rem >> 2;
  const int m0 = bm << 8;
  const int n0 = bn << 8;

  // Staging source (invert cell map): lane writes cell=lane of (block w, page ks).
  // u = (lane&3) ^ ((lane>>3)&3); row-in-block = (lane>>2) + 16*(u&1);
  // chunk-within-page cb = (u>>1)&1; k offset = 32h + ks*16 + cb*8.
  const int iu = (l & 3) ^ ((l >> 3) & 3);
  const int srow = 32 * w + (l >> 2) + 16 * (iu & 1);
  const int scol = ((iu >> 1) & 1) << 3;
  const unsigned short* gA0 = A + (size_t)(m0 + srow) * 4096 + scol;
  const unsigned short* gB0 = B + (size_t)(n0 + srow) * 4096 + scol;

  // Read offset within a page (round-7-certified pattern):
  const int rdoff = (l & 15) * 32 + (((((l >> 4) & 3) ^ ((l >> 1) & 3))) << 3);
  const int aBlk = wm * 4096;   // block (wm*4 + mi) -> + mi*1024
  const int bBlk = wn * 2048;   // block (wn*2 + nj) -> + nj*1024

  auto stage = [&](const unsigned short* g0, int h, int isB) {
    const int slot = h & 3;
#pragma unroll
    for (int ks = 0; ks < 2; ++ks)
      __builtin_amdgcn_global_load_lds(
          (const __attribute__((address_space(1))) void*)(g0 + h * 32 + ks * 16),
          (__attribute__((address_space(3))) void*)((char*)lds + isB * 65536 + slot * 16384 + w * 2048 + ks * 1024),
          16, 0, 0);
  };

  f32x16 acc[4][2] = {};
  bf16x8 afr[4], bfr[4];

  // Prologue: stage halves 0,1,2 (12 loads); vmcnt(8) -> half 0 landed.
  stage(gA0, 0, 0); stage(gB0, 0, 1);
  stage(gA0, 1, 0); stage(gB0, 1, 1);
  stage(gA0, 2, 0); stage(gB0, 2, 1);
  asm volatile("s_waitcnt vmcnt(8)" ::: "memory");
  __builtin_amdgcn_s_barrier();

#define MFMA32(a, b, c) __builtin_amdgcn_mfma_f32_32x32x16_bf16(a, b, c, 0, 0, 0)

#define PH0(HV, SLOT)                                                          \
  {                                                                            \
    const unsigned short* aL = lds + (SLOT) * 8192 + aBlk + rdoff;             \
    const unsigned short* bL = lds + 32768 + (SLOT) * 8192 + bBlk + rdoff;     \
    afr[0] = *(const bf16x8*)(aL);                /* mi0 ks0 */                \
    afr[1] = *(const bf16x8*)(aL + 512);          /* mi0 ks1 */                \
    afr[2] = *(const bf16x8*)(aL + 1024);         /* mi1 ks0 */                \
    afr[3] = *(const bf16x8*)(aL + 1536);         /* mi1 ks1 */                \
    bfr[0] = *(const bf16x8*)(bL);                /* nj0 ks0 */                \
    bfr[1] = *(const bf16x8*)(bL + 512);          /* nj0 ks1 */                \
    bfr[2] = *(const bf16x8*)(bL + 1024);         /* nj1 ks0 */                \
    bfr[3] = *(const bf16x8*)(bL + 1536);         /* nj1 ks1 */                \
    if ((HV) <= 124) stage(gA0, (HV) + 3, 0);                                  \
    __builtin_amdgcn_s_barrier();                                              \
    asm volatile("s_waitcnt lgkmcnt(0)" ::: "memory");                         \
    __builtin_amdgcn_sched_barrier(0);                                         \
    __builtin_amdgcn_s_setprio(1);                                             \
    acc[0][0] = MFMA32(afr[0], bfr[0], acc[0][0]);                             \
    acc[0][1] = MFMA32(afr[0], bfr[2], acc[0][1]);                             \
    acc[1][0] = MFMA32(afr[2], bfr[0], acc[1][0]);                             \
    acc[1][1] = MFMA32(afr[2], bfr[2], acc[1][1]);                             \
    acc[0][0] = MFMA32(afr[1], bfr[1], acc[0][0]);                             \
    acc[0][1] = MFMA32(afr[1], bfr[3], acc[0][1]);                             \
    acc[1][0] = MFMA32(afr[3], bfr[1], acc[1][0]);                             \
    acc[1][1] = MFMA32(afr[3], bfr[3], acc[1][1]);                             \
    __builtin_amdgcn_s_setprio(0);                                             \
    __builtin_amdgcn_s_barrier();                                              \
  }

#define PH1(HV, SLOT)                                                          \
  {                                                                            \
    const unsigned short* aL = lds + (SLOT) * 8192 + aBlk + 2048 + rdoff;      \
    afr[0] = *(const bf16x8*)(aL);                /* mi2 ks0 */                \
    afr[1] = *(const bf16x8*)(aL + 512);          /* mi2 ks1 */                \
    afr[2] = *(const bf16x8*)(aL + 1024);         /* mi3 ks0 */                \
    afr[3] = *(const bf16x8*)(aL + 1536);         /* mi3 ks1 */                \
    if ((HV) <= 124) stage(gB0, (HV) + 3, 1);                                  \
    __builtin_amdgcn_s_barrier();                                              \
    asm volatile("s_waitcnt lgkmcnt(0)" ::: "memory");                         \
    __builtin_amdgcn_sched_barrier(0);                                         \
    __builtin_amdgcn_s_setprio(1);                                             \
    acc[2][0] = MFMA32(afr[0], bfr[0], acc[2][0]);                             \
    acc[2][1] = MFMA32(afr[0], bfr[2], acc[2][1]);                             \
    acc[3][0] = MFMA32(afr[2], bfr[0], acc[3][0]);                             \
    acc[3][1] = MFMA32(afr[2], bfr[2], acc[3][1]);                             \
    acc[2][0] = MFMA32(afr[1], bfr[1], acc[2][0]);                             \
    acc[2][1] = MFMA32(afr[1], bfr[3], acc[2][1]);                             \
    acc[3][0] = MFMA32(afr[3], bfr[1], acc[3][0]);                             \
    acc[3][1] = MFMA32(afr[3], bfr[3], acc[3][1]);                             \
    __builtin_amdgcn_s_setprio(0);                                             \
    if ((HV) <= 124)      asm volatile("s_waitcnt vmcnt(8)" ::: "memory");     \
    else if ((HV) == 125) asm volatile("s_waitcnt vmcnt(4)" ::: "memory");     \
    else if ((HV) == 126) asm volatile("s_waitcnt vmcnt(0)" ::: "memory");     \
    __builtin_amdgcn_s_barrier();                                              \
  }

  for (int h = 0; h < 128; h += 4) {
    PH0(h + 0, 0) PH1(h + 0, 0)
    PH0(h + 1, 1) PH1(h + 1, 1)
    PH0(h + 2, 2) PH1(h + 2, 2)
    PH0(h + 3, 3) PH1(h + 3, 3)
  }
#undef PH0
#undef PH1
#undef MFMA32

  // Epilogue: C[m,n] = acc * v[n]. 32x32 C/D: col = l&31,
  // row = (reg&3) + 8*(reg>>2) + 4*(l>>5).
  const int ccol = l & 31;
  const int rbase = 4 * (l >> 5);
#pragma unroll
  for (int nj = 0; nj < 2; ++nj) {
    const int colj = n0 + wn * 64 + nj * 32 + ccol;
    const float vs = vscale[colj];
#pragma unroll
    for (int mi = 0; mi < 4; ++mi) {
      const int row0 = m0 + wm * 128 + mi * 32 + rbase;
#pragma unroll
      for (int r = 0; r < 16; ++r) {
        const int rowi = row0 + (r & 3) + 8 * (r >> 2);
        C[((size_t)rowi << 12) + colj] = acc[mi][nj][r] * vs;
      }
    }
  }
}

extern "C" void kernel_launch(void* const* d_in, const int* in_sizes, int n_in,
                              void* d_out, int out_size, void* d_ws, size_t ws_size,
                              hipStream_t stream) {
  const float* x      = (const float*)d_in[0];   // [4,2048,4096] f32
  const float* weight = (const float*)d_in[1];   // [4096,4096] f32
  const float* c_prev = (const float*)d_in[3];   // [1,4096] f32; r_prev unused
  float* out = (float*)d_out;

  char* ws = (char*)d_ws;
  float* u = (float*)ws;                                   // 4096 f32
  float* v = (float*)(ws + (16 << 10));                    // 4096 f32
  unsigned short* E  = (unsigned short*)(ws + (64 << 10)); // 33.5 MB
  unsigned short* ET = E + (size_t)4096 * 4096;            // 33.5 MB (dead after iters)
  unsigned short* xb = ET;                                 // xb overlays ET (67 MB)

  prep_e<<<4096, 256, 0, stream>>>(weight, E);
  transpose_bf<<<dim3(64, 64), 256, 0, stream>>>(E, ET);
  init_u<<<16, 256, 0, stream>>>(c_prev, u);

  for (int it = 0; it < 10; ++it) {
    recip_mv<<<1024, 256, 0, stream>>>(E, u, v);   // v = 1/(E u)
    recip_mv<<<1024, 256, 0, stream>>>(ET, v, u);  // u = 1/(E^T v)
  }

  scale_x<<<32768, 256, 0, stream>>>(x, u, xb);    // xb = bf16(x * u), kills ET

  gemm_bt<<<512, 512, 0, stream>>>(xb, E, v, out);
}

// Round 11
// 447.174 us; speedup vs baseline: 1.0452x; 1.0352x over previous
//
#include <hip/hip_runtime.h>

// WarmStartSinkhornLinear on MI355X — round 11.
// Scaling-form Sinkhorn + 256x256 bf16 GEMM (16x16x32 MFMA, round-7 layout).
// Round-11 change: reads skewed ONE PHASE ahead of consumption with COUNTED
// lgkmcnt (4/8) instead of lgkmcnt(0). Round 7's {reads, bar, lgkm0, MFMA}
// serialized LDS-pipe time and MFMA (2306 cyc/half ~= serial sum 1152+1242);
// the skew lets reads stream under the MFMA clusters. All other structure
// (4-slot ring, chunk-XOR swizzle phys=c^((r>>1)&3) [HW-certified 0-conflict],
// 3-ahead staging, vmcnt(6) gate, XCD swizzle) unchanged from round 7.

#define L2E 1.44269504088896340736f

typedef __attribute__((ext_vector_type(8))) short bf16x8;
typedef __attribute__((ext_vector_type(4))) float f32x4;

__device__ __forceinline__ unsigned short f2bf(float x) {
  unsigned u = __float_as_uint(x);
  u += 0x7fffu + ((u >> 16) & 1u);  // RNE
  return (unsigned short)(u >> 16);
}
__device__ __forceinline__ float bf2f(short x) {
  return __uint_as_float(((unsigned)(unsigned short)x) << 16);
}

// ---- E[row,:] = bf16(exp(10*W[row,:] - rowmax)); one block per row.
__global__ void prep_e(const float* __restrict__ W, unsigned short* __restrict__ E) {
  const int row = blockIdx.x;
  const int t = threadIdx.x;
  const float* wp = W + ((size_t)row << 12);
  float v[16];
  float m = -3.4e38f;
#pragma unroll
  for (int ch = 0; ch < 4; ++ch) {
    float4 wv = *(const float4*)(wp + ch * 1024 + t * 4);
    float a0 = 10.f * wv.x, a1 = 10.f * wv.y, a2 = 10.f * wv.z, a3 = 10.f * wv.w;
    v[ch * 4 + 0] = a0; v[ch * 4 + 1] = a1; v[ch * 4 + 2] = a2; v[ch * 4 + 3] = a3;
    m = fmaxf(m, fmaxf(fmaxf(a0, a1), fmaxf(a2, a3)));
  }
#pragma unroll
  for (int off = 32; off > 0; off >>= 1) m = fmaxf(m, __shfl_xor(m, off));
  __shared__ float sm[4];
  if ((t & 63) == 0) sm[t >> 6] = m;
  __syncthreads();
  m = fmaxf(fmaxf(sm[0], sm[1]), fmaxf(sm[2], sm[3]));
  unsigned short* ep = E + ((size_t)row << 12);
#pragma unroll
  for (int ch = 0; ch < 4; ++ch) {
    ushort4 o;
    o.x = f2bf(exp2f((v[ch * 4 + 0] - m) * L2E));
    o.y = f2bf(exp2f((v[ch * 4 + 1] - m) * L2E));
    o.z = f2bf(exp2f((v[ch * 4 + 2] - m) * L2E));
    o.w = f2bf(exp2f((v[ch * 4 + 3] - m) * L2E));
    *(ushort4*)(ep + ch * 1024 + t * 4) = o;
  }
}

// ---- ET[j][i] = E[i][j]; 64x64 bf16 tiles via LDS.
__global__ void transpose_bf(const unsigned short* __restrict__ E,
                             unsigned short* __restrict__ ET) {
  __shared__ unsigned short tile[64][66];
  const int t = threadIdx.x;
  const int r = t >> 3;
  const int c8 = (t & 7) << 3;
  const size_t i0 = (size_t)blockIdx.y << 6;
  const size_t j0 = (size_t)blockIdx.x << 6;
#pragma unroll
  for (int h = 0; h < 2; ++h) {
    bf16x8 vv = *(const bf16x8*)(E + (i0 + h * 32 + r) * 4096 + j0 + c8);
#pragma unroll
    for (int e = 0; e < 8; ++e) tile[h * 32 + r][c8 + e] = (unsigned short)vv[e];
  }
  __syncthreads();
#pragma unroll
  for (int h = 0; h < 2; ++h) {
    bf16x8 vv;
#pragma unroll
    for (int e = 0; e < 8; ++e) vv[e] = (short)tile[c8 + e][h * 32 + r];
    *(bf16x8*)(ET + (j0 + h * 32 + r) * 4096 + i0 + c8) = vv;
  }
}

// ---- u[i] = exp(c_prev[i])
__global__ void init_u(const float* __restrict__ c_prev, float* __restrict__ u) {
  const int i = blockIdx.x * 256 + threadIdx.x;
  u[i] = exp2f(c_prev[i] * L2E);
}

// ---- out[row] = 1 / sum_j M[row][j]*uin[j]; 1 wave per row, 4 rows/block.
__global__ void recip_mv(const unsigned short* __restrict__ M,
                         const float* __restrict__ uin, float* __restrict__ vout) {
  const int t = threadIdx.x;
  const int l = t & 63, w = t >> 6;
  const int row = (blockIdx.x << 2) + w;
  const unsigned short* mp = M + ((size_t)row << 12);
  float s = 0.f;
#pragma unroll
  for (int ch = 0; ch < 8; ++ch) {
    const int j = (ch << 9) + (l << 3);
    bf16x8 e = *(const bf16x8*)(mp + j);
    const float4 u0 = *(const float4*)(uin + j);
    const float4 u1 = *(const float4*)(uin + j + 4);
    s = fmaf(bf2f(e[0]), u0.x, s);
    s = fmaf(bf2f(e[1]), u0.y, s);
    s = fmaf(bf2f(e[2]), u0.z, s);
    s = fmaf(bf2f(e[3]), u0.w, s);
    s = fmaf(bf2f(e[4]), u1.x, s);
    s = fmaf(bf2f(e[5]), u1.y, s);
    s = fmaf(bf2f(e[6]), u1.z, s);
    s = fmaf(bf2f(e[7]), u1.w, s);
  }
#pragma unroll
  for (int off = 32; off > 0; off >>= 1) s += __shfl_xor(s, off);
  if (l == 0) vout[row] = 1.f / s;
}

// ---- xb[t,j] = bf16(x[t,j] * u[j])
__global__ void scale_x(const float* __restrict__ X, const float* __restrict__ u,
                        unsigned short* __restrict__ Y) {
  const size_t idx = ((size_t)blockIdx.x * 256 + threadIdx.x) * 4;
  const int col = (int)(idx & 4095);
  float4 xv = *(const float4*)(X + idx);
  float4 uu = *(const float4*)(u + col);
  ushort4 o;
  o.x = f2bf(xv.x * uu.x);
  o.y = f2bf(xv.y * uu.y);
  o.z = f2bf(xv.z * uu.z);
  o.w = f2bf(xv.w * uu.w);
  *(ushort4*)(Y + idx) = o;
}

// ---- C[m,n] = v[n] * sum_k A[m,k]*B[n,k]; A [8192,4096], B [4096,4096] bf16.
// 256x256 tile, 8 waves (2Mx4N), wave tile 128x64 (8Mx4N frags of 16x16x32).
// k-half h = 32 K; slot = h&3 ([256r][32k], phys chunk = c^((r>>1)&3)).
// P0(h): rd A4-7(h); stage A(h+3); vmcnt(6); bar; lgkm(4); MFMA mi0-3; bar.
// P1(h): rd A0-3(h+1)+B0-3(h+1)->BNXT; stage B(h+3); bar; lgkm(8); MFMA mi4-7; bar.
// Hazards: WAR on slot (h-1)&3 (stageA@P0(h)): all slot reads are older than
// P1(h-1)'s lgkm(8) window -> done before its closing barrier. RAW on slot h+1:
// vmcnt(6)@P0(h) drains through B(h+1) (order A..,B(h+1),A(h+2),B(h+2),A(h+3)).
// Tails: vmcnt 4/0 at h=125/126; lgkm(0) at P1(127).
__global__ __launch_bounds__(512, 2) void gemm_bt(const unsigned short* __restrict__ A,
                                                  const unsigned short* __restrict__ B,
                                                  const float* __restrict__ vscale,
                                                  float* __restrict__ C) {
  __shared__ unsigned short lds[65536];  // 128 KB
  const int t = threadIdx.x;
  const int l = t & 63;
  const int w = t >> 6;          // 0..7
  const int wm = w >> 2, wn = w & 3;

  // XCD-bijective swizzle (512 % 8 == 0) + GROUP_M=4
  int pid = blockIdx.x;
  pid = (pid & 7) * 64 + (pid >> 3);
  const int grp = pid >> 6;
  const int rem = pid & 63;
  const int bm = (grp << 2) + (rem & 3);
  const int bn = rem >> 2;
  const int m0 = bm << 8;
  const int n0 = bn << 8;

  // staging: thread t writes LDS row (t>>2), physical chunk (t&3); fetch the
  // logical chunk that belongs there: logical = (t&3) ^ f(row), f(r)=(r>>1)&3.
  const int ca = (((t & 3) ^ ((t >> 3) & 3)) << 3);
  const unsigned short* gA = A + (size_t)(m0 + (t >> 2)) * 4096 + ca;
  const unsigned short* gB = B + (size_t)(n0 + (t >> 2)) * 4096 + ca;

  // ds_read: lane l, logical chunk (l>>4) of row (l&15) -> physical =
  // (l>>4) ^ ((l>>1)&3). HW-certified conflict-free (rounds 4-7).
  const int xc = (((l >> 4) ^ ((l >> 1) & 3)) << 3);
  const int aOff = (wm * 128 + (l & 15)) * 32 + xc;
  const int bOff = (wn * 64 + (l & 15)) * 32 + xc;

  auto stageA = [&](int kt) {
    const int b = kt & 3;
    const unsigned short* g = gA + (size_t)kt * 32;
#pragma unroll
    for (int ra = 0; ra < 2; ++ra)
      __builtin_amdgcn_global_load_lds(
          (const __attribute__((address_space(1))) void*)(g + (size_t)ra * 524288),
          (__attribute__((address_space(3))) void*)((char*)lds + b * 16384 + ra * 8192 + w * 1024),
          16, 0, 0);
  };
  auto stageB = [&](int kt) {
    const int b = kt & 3;
    const unsigned short* g = gB + (size_t)kt * 32;
#pragma unroll
    for (int ra = 0; ra < 2; ++ra)
      __builtin_amdgcn_global_load_lds(
          (const __attribute__((address_space(1))) void*)(g + (size_t)ra * 524288),
          (__attribute__((address_space(3))) void*)((char*)lds + 65536 + b * 16384 + ra * 8192 + w * 1024),
          16, 0, 0);
  };

  f32x4 acc[8][4] = {};
  bf16x8 aLo[4], aHi[4], Bc0[4], Bc1[4];

  // Prologue: stage A0,B0,A1,B1,A2,B2 (12 loads, this order); vmcnt(8) ->
  // A0,B0 landed; barrier; read A0-3(0)->aLo, B0-3(0)->Bc0 (8 reads).
  stageA(0); stageB(0);
  stageA(1); stageB(1);
  stageA(2); stageB(2);
  asm volatile("s_waitcnt vmcnt(8)" ::: "memory");
  __builtin_amdgcn_s_barrier();
#pragma unroll
  for (int i = 0; i < 4; ++i) aLo[i] = *(const bf16x8*)(lds + aOff + i * 512);
#pragma unroll
  for (int j = 0; j < 4; ++j) Bc0[j] = *(const bf16x8*)(lds + 32768 + bOff + j * 512);

#define MF(a, b, c) __builtin_amdgcn_mfma_f32_16x16x32_bf16(a, b, c, 0, 0, 0)

#define P0(HV, BC)                                                             \
  {                                                                            \
    const unsigned short* aL = lds + ((HV) & 3) * 8192 + aOff;                 \
    _Pragma("unroll")                                                          \
    for (int i = 0; i < 4; ++i) aHi[i] = *(const bf16x8*)(aL + (4 + i) * 512); \
    if ((HV) <= 124) stageA((HV) + 3);                                         \
    if ((HV) <= 124)      asm volatile("s_waitcnt vmcnt(6)" ::: "memory");     \
    else if ((HV) == 125) asm volatile("s_waitcnt vmcnt(4)" ::: "memory");     \
    else if ((HV) == 126) asm volatile("s_waitcnt vmcnt(0)" ::: "memory");     \
    __builtin_amdgcn_sched_barrier(0);                                         \
    __builtin_amdgcn_s_barrier();                                              \
    asm volatile("s_waitcnt lgkmcnt(4)" ::: "memory");                         \
    __builtin_amdgcn_sched_barrier(0);                                         \
    __builtin_amdgcn_s_setprio(1);                                             \
    _Pragma("unroll")                                                          \
    for (int i = 0; i < 4; ++i)                                                \
      _Pragma("unroll")                                                        \
      for (int j = 0; j < 4; ++j)                                              \
        acc[i][j] = MF(aLo[i], BC[j], acc[i][j]);                              \
    __builtin_amdgcn_s_setprio(0);                                             \
    __builtin_amdgcn_s_barrier();                                              \
  }

#define P1(HV, BC, BN)                                                         \
  {                                                                            \
    if ((HV) <= 126) {                                                         \
      const unsigned short* aN = lds + (((HV) + 1) & 3) * 8192 + aOff;         \
      const unsigned short* bN = lds + 32768 + (((HV) + 1) & 3) * 8192 + bOff; \
      _Pragma("unroll")                                                        \
      for (int i = 0; i < 4; ++i) aLo[i] = *(const bf16x8*)(aN + i * 512);     \
      _Pragma("unroll")                                                        \
      for (int j = 0; j < 4; ++j) BN[j] = *(const bf16x8*)(bN + j * 512);      \
    }                                                                          \
    if ((HV) <= 124) stageB((HV) + 3);                                         \
    __builtin_amdgcn_sched_barrier(0);                                         \
    __builtin_amdgcn_s_barrier();                                              \
    if ((HV) <= 126) asm volatile("s_waitcnt lgkmcnt(8)" ::: "memory");        \
    else             asm volatile("s_waitcnt lgkmcnt(0)" ::: "memory");        \
    __builtin_amdgcn_sched_barrier(0);                                         \
    __builtin_amdgcn_s_setprio(1);                                             \
    _Pragma("unroll")                                                          \
    for (int i = 0; i < 4; ++i)                                                \
      _Pragma("unroll")                                                        \
      for (int j = 0; j < 4; ++j)                                              \
        acc[4 + i][j] = MF(aHi[i], BC[j], acc[4 + i][j]);                      \
    __builtin_amdgcn_s_setprio(0);                                             \
    __builtin_amdgcn_s_barrier();                                              \
  }

  for (int h = 0; h < 128; h += 2) {
    P0(h, Bc0) P1(h, Bc0, Bc1)
    P0(h + 1, Bc1) P1(h + 1, Bc1, Bc0)
  }
#undef P0
#undef P1
#undef MF

  // Epilogue: C[m,n] = acc * v[n]
  const int crow = (l >> 4) << 2;
  const int ccol = l & 15;
#pragma unroll
  for (int j = 0; j < 4; ++j) {
    const int colj = n0 + (wn << 6) + (j << 4) + ccol;
    const float vs = vscale[colj];
#pragma unroll
    for (int i = 0; i < 8; ++i) {
      const int rowi = m0 + (wm << 7) + (i << 4) + crow;
#pragma unroll
      for (int q = 0; q < 4; ++q)
        C[((size_t)(rowi + q) << 12) + colj] = acc[i][j][q] * vs;
    }
  }
}

extern "C" void kernel_launch(void* const* d_in, const int* in_sizes, int n_in,
                              void* d_out, int out_size, void* d_ws, size_t ws_size,
                              hipStream_t stream) {
  const float* x      = (const float*)d_in[0];   // [4,2048,4096] f32
  const float* weight = (const float*)d_in[1];   // [4096,4096] f32
  const float* c_prev = (const float*)d_in[3];   // [1,4096] f32; r_prev unused
  float* out = (float*)d_out;

  char* ws = (char*)d_ws;
  float* u = (float*)ws;                                   // 4096 f32
  float* v = (float*)(ws + (16 << 10));                    // 4096 f32
  unsigned short* E  = (unsigned short*)(ws + (64 << 10)); // 33.5 MB
  unsigned short* ET = E + (size_t)4096 * 4096;            // 33.5 MB (dead after iters)
  unsigned short* xb = ET;                                 // xb overlays ET (67 MB)

  prep_e<<<4096, 256, 0, stream>>>(weight, E);
  transpose_bf<<<dim3(64, 64), 256, 0, stream>>>(E, ET);
  init_u<<<16, 256, 0, stream>>>(c_prev, u);

  for (int it = 0; it < 10; ++it) {
    recip_mv<<<1024, 256, 0, stream>>>(E, u, v);   // v = 1/(E u)
    recip_mv<<<1024, 256, 0, stream>>>(ET, v, u);  // u = 1/(E^T v)
  }

  scale_x<<<32768, 256, 0, stream>>>(x, u, xb);    // xb = bf16(x * u), kills ET

  gemm_bt<<<512, 512, 0, stream>>>(xb, E, v, out);
}